// Round 1
// baseline (334.292 us; speedup 1.0000x reference)
//
#include <hip/hip_runtime.h>
#include <math.h>

#define N_   200
#define B_   512
#define K1_  100
#define K2_  50

// out layout: logp [512*2] | s1 [512*100] | s2 [512*50]
#define S1_OFF 1024
#define S2_OFF 52224

__device__ __forceinline__ float lrelu(float v) { return v > 0.f ? v : 0.2f * v; }
__device__ __forceinline__ float sigm(float v)  { return 1.f / (1.f + __expf(-v)); }

__device__ __forceinline__ void bitonic_desc(float* key, int* idx, int n, int t) {
  for (int k = 2; k <= n; k <<= 1) {
    for (int j = k >> 1; j > 0; j >>= 1) {
      __syncthreads();
      int ixj = t ^ j;
      if (t < n && ixj > t) {
        float a = key[t], c = key[ixj];
        int ia = idx[t], ic = idx[ixj];
        bool gt = (a > c) || (a == c && ia < ic);
        if (((t & k) == 0) ? !gt : gt) {
          key[t] = c; key[ixj] = a; idx[t] = ic; idx[ixj] = ia;
        }
      }
    }
  }
  __syncthreads();
}

// LDS overlay map (bytes), total 63792 (<64KB -> 2 blocks/CU):
//     0 : sH    25600  h(200x32) phases A-B; h2a(100x32) phase E
// 25600 : sH1   25600  h1(200x32) B-C; h2(100x32) E-F (rows 0..99 only)
// 38400 : sXK   12800  xk(100x32) C-E; xk2(50x32) F   [aliases h1 rows 100..199]
// 51200 : sES     800
// 52000 : sED     800
// 52800 : sBITS  5600  adj>0 bitmask, B-D;  sW2 4096 phase E (alias)
// 58400 : sKey   1024
// 59424 : sIdx   1024
// 60448 : sSel    400
// 60848 : sVal    400
// 61248 : sXV     512  [x1 | x2] pooled features
// 61760 : sRed     32
// 61792 : sMask2 2000  2-hop mask, 100 rows x stride 5 u32

__global__ __launch_bounds__(256) void gnn_fused(
    const float* __restrict__ x, const float* __restrict__ adj,
    const float* __restrict__ W1, const float* __restrict__ a1s,
    const float* __restrict__ a1d, const float* __restrict__ b1,
    const float* __restrict__ W2g, const float* __restrict__ a2s,
    const float* __restrict__ a2d, const float* __restrict__ b2,
    const float* __restrict__ pw1, const float* __restrict__ pw2,
    const float* __restrict__ fc1w, const float* __restrict__ fc1b,
    const float* __restrict__ fc2w, const float* __restrict__ fc2b,
    const float* __restrict__ fc3w, const float* __restrict__ fc3b,
    const float* __restrict__ bn4g, const float* __restrict__ bn4b,
    const float* __restrict__ bn5g, const float* __restrict__ bn5b,
    float* __restrict__ out)
{
  __shared__ __align__(16) char smem[63792];
  float*    sH    = (float*)smem;
  float*    sH1   = (float*)(smem + 25600);
  float*    sXK   = (float*)(smem + 38400);
  float*    sES   = (float*)(smem + 51200);
  float*    sED   = (float*)(smem + 52000);
  unsigned* sBITS = (unsigned*)(smem + 52800);
  float*    sW2   = (float*)(smem + 52800);   // alias, used after sBITS dead
  float*    sKey  = (float*)(smem + 58400);
  int*      sIdx  = (int*)(smem + 59424);
  int*      sSel  = (int*)(smem + 60448);
  float*    sVal  = (float*)(smem + 60848);
  float*    sXV   = (float*)(smem + 61248);
  float*    sRed  = (float*)(smem + 61760);
  unsigned* sMask2= (unsigned*)(smem + 61792);

  const int t = threadIdx.x;
  const int b = blockIdx.x;
  const float* xb = x   + (size_t)b * N_ * N_;
  const float* ab = adj + (size_t)b * N_ * N_;

  // ---------------- Phase A: h = x @ W1 ; es, ed ----------------
  if (t < N_) {
    float acc[32];
    #pragma unroll
    for (int d = 0; d < 32; ++d) acc[d] = 0.f;
    const float* xr = xb + t * N_;
    for (int k = 0; k < N_; k += 4) {
      float4 xv = *(const float4*)(xr + k);
      #pragma unroll
      for (int kk = 0; kk < 4; ++kk) {
        float xs = (&xv.x)[kk];
        const float* wr = W1 + (k + kk) * 32;   // uniform -> scalar loads
        #pragma unroll
        for (int d = 0; d < 32; ++d) acc[d] += xs * wr[d];
      }
    }
    float es = 0.f, ed = 0.f;
    #pragma unroll
    for (int d = 0; d < 32; ++d) { es += acc[d] * a1s[d]; ed += acc[d] * a1d[d]; }
    sES[t] = es; sED[t] = ed;
    #pragma unroll
    for (int d = 0; d < 32; ++d) sH[t * 32 + d] = acc[d];
  }
  __syncthreads();

  // esmax over all nodes (safe softmax bound; leaky_relu is monotone)
  {
    float v = (t < N_) ? sES[t] : -3.0e38f;
    #pragma unroll
    for (int off = 1; off < 64; off <<= 1) v = fmaxf(v, __shfl_xor(v, off, 64));
    if ((t & 63) == 0) sRed[t >> 6] = v;
  }
  __syncthreads();
  {
    float esmax = fmaxf(fmaxf(sRed[0], sRed[1]), fmaxf(sRed[2], sRed[3]));

    // -------------- Phase B: GAT1 masked-softmax aggregate --------------
    if (t < N_) {
      const float* arow = ab + (size_t)t * N_;
      float ed_i = sED[t];
      float L = lrelu(ed_i + esmax);
      float ssum = 0.f;
      float acc[32];
      #pragma unroll
      for (int d = 0; d < 32; ++d) acc[d] = 0.f;
      for (int jw = 0; jw < 7; ++jw) {
        int jbase = jw * 32;
        int cnt = (jw < 6) ? 32 : 8;
        unsigned mb = 0u;
        for (int j4 = 0; j4 < cnt; j4 += 4) {
          float4 av = *(const float4*)(arow + jbase + j4);
          #pragma unroll
          for (int jj = 0; jj < 4; ++jj) {
            int j = jbase + j4 + jj;
            float a = (&av.x)[jj];
            bool conn = a > 0.f;
            if (conn) mb |= (1u << (j4 + jj));
            float w = 0.f;
            if (conn || j == t) w = __expf(lrelu(ed_i + sES[j]) - L);
            ssum += w;
            const float* hr = &sH[j * 32];          // uniform addr -> broadcast
            #pragma unroll
            for (int d = 0; d < 32; ++d) acc[d] += w * hr[d];
          }
        }
        sBITS[t * 7 + jw] = mb;
      }
      float inv = 1.f / ssum;
      #pragma unroll
      for (int d = 0; d < 32; ++d) sH1[t * 32 + d] = acc[d] * inv + b1[d];
    }
  }
  __syncthreads();

  // -------------- Phase C: TopK pool 1 --------------
  {
    float npw = 0.f;
    #pragma unroll
    for (int d = 0; d < 32; ++d) npw += pw1[d] * pw1[d];
    npw = sqrtf(npw) + 1e-16f;
    float sc = -1.f;
    if (t < N_) {
      float dp = 0.f;
      #pragma unroll
      for (int d = 0; d < 32; ++d) dp += sH1[t * 32 + d] * pw1[d];
      sc = sigm(dp / npw);
    }
    sKey[t] = sc; sIdx[t] = t;
  }
  bitonic_desc(sKey, sIdx, 256, t);
  if (t < K1_) {
    out[S1_OFF + b * K1_ + t] = sKey[t];
    sVal[t] = sKey[t]; sSel[t] = sIdx[t];
  }
  __syncthreads();
  // xk = h1[sel]*val. sXK aliases h1 rows 100..199 -> stage through registers.
  {
    float tmp[13];
    #pragma unroll
    for (int it = 0; it < 13; ++it) {
      int i = t + it * 256;
      if (i < K1_ * 32) tmp[it] = sH1[sSel[i >> 5] * 32 + (i & 31)] * sVal[i >> 5];
    }
    __syncthreads();
    #pragma unroll
    for (int it = 0; it < 13; ++it) {
      int i = t + it * 256;
      if (i < K1_ * 32) sXK[i] = tmp[it];
    }
  }
  __syncthreads();
  // x1 = [max, mean] over 100 pooled nodes
  if (t < 32) {
    float m = -3.0e38f, s = 0.f;
    for (int r = 0; r < K1_; ++r) { float v = sXK[r * 32 + t]; m = fmaxf(m, v); s += v; }
    sXV[t] = m; sXV[32 + t] = s / 100.f;
  }

  // -------------- Phase D: 2-hop mask (a2 != 0 | eye), boolean bitsets --------------
  if (t < K1_) {
    int gi = sSel[t];
    #pragma unroll
    for (int w = 0; w < 4; ++w) {
      unsigned m = 0;
      const int lim = (w < 3) ? 32 : 4;
      for (int jj = 0; jj < lim; ++jj) {
        int j = w * 32 + jj;
        int gj = sSel[j];
        unsigned bit = (sBITS[gi * 7 + (gj >> 5)] >> (gj & 31)) & 1u;
        if (j == t) bit = 1u;                       // (A+I) self loop
        m |= bit << jj;
      }
      sMask2[t * 5 + w] = m;
    }
  }
  __syncthreads();
  {
    unsigned pr0 = 0, pr1 = 0, pr2 = 0, pr3 = 0;
    if (t < K1_) {
      #pragma unroll
      for (int kw = 0; kw < 4; ++kw) {
        unsigned mk = sMask2[t * 5 + kw];
        const int lim = (kw < 3) ? 32 : 4;
        for (int kk = 0; kk < lim; ++kk) {
          if ((mk >> kk) & 1u) {
            int k = kw * 32 + kk;
            pr0 |= sMask2[k * 5 + 0]; pr1 |= sMask2[k * 5 + 1];
            pr2 |= sMask2[k * 5 + 2]; pr3 |= sMask2[k * 5 + 3];
          }
        }
      }
    }
    __syncthreads();
    if (t < K1_) {
      sMask2[t * 5 + 0] = pr0; sMask2[t * 5 + 1] = pr1;
      sMask2[t * 5 + 2] = pr2; sMask2[t * 5 + 3] = pr3;
    }
  }
  __syncthreads();

  // -------------- Phase E: GAT2 --------------
  for (int i = t; i < 1024; i += 256) sW2[i] = W2g[i];   // sBITS dead now
  __syncthreads();
  if (t < K1_) {
    float acc[32];
    #pragma unroll
    for (int d = 0; d < 32; ++d) acc[d] = 0.f;
    for (int k = 0; k < 32; ++k) {
      float xv = sXK[t * 32 + k];
      const float* wr = &sW2[k * 32];
      #pragma unroll
      for (int d = 0; d < 32; ++d) acc[d] += xv * wr[d];
    }
    float es = 0.f, ed = 0.f;
    #pragma unroll
    for (int d = 0; d < 32; ++d) { es += acc[d] * a2s[d]; ed += acc[d] * a2d[d]; }
    sES[t] = es; sED[t] = ed;
    #pragma unroll
    for (int d = 0; d < 32; ++d) sH[t * 32 + d] = acc[d];
  }
  __syncthreads();
  {
    float v = (t < K1_) ? sES[t] : -3.0e38f;
    #pragma unroll
    for (int off = 1; off < 64; off <<= 1) v = fmaxf(v, __shfl_xor(v, off, 64));
    if ((t & 63) == 0) sRed[t >> 6] = v;
  }
  __syncthreads();
  {
    float esm2 = fmaxf(fmaxf(sRed[0], sRed[1]), fmaxf(sRed[2], sRed[3]));
    if (t < K1_) {
      float ed_i = sED[t];
      float L = lrelu(ed_i + esm2);
      float ssum = 0.f;
      float acc[32];
      #pragma unroll
      for (int d = 0; d < 32; ++d) acc[d] = 0.f;
      #pragma unroll
      for (int jw = 0; jw < 4; ++jw) {
        unsigned mw = sMask2[t * 5 + jw];
        const int lim = (jw < 3) ? 32 : 4;
        for (int jj = 0; jj < lim; ++jj) {
          int j = jw * 32 + jj;
          float w = 0.f;
          if ((mw >> jj) & 1u) w = __expf(lrelu(ed_i + sES[j]) - L);
          ssum += w;
          const float* hr = &sH[j * 32];
          #pragma unroll
          for (int d = 0; d < 32; ++d) acc[d] += w * hr[d];
        }
      }
      float inv = 1.f / ssum;
      #pragma unroll
      for (int d = 0; d < 32; ++d) sH1[t * 32 + d] = acc[d] * inv + b2[d];
    }
  }
  __syncthreads();

  // -------------- Phase F: TopK pool 2 --------------
  {
    float npw = 0.f;
    #pragma unroll
    for (int d = 0; d < 32; ++d) npw += pw2[d] * pw2[d];
    npw = sqrtf(npw) + 1e-16f;
    float sc = -1.f;
    if (t < K1_) {
      float dp = 0.f;
      #pragma unroll
      for (int d = 0; d < 32; ++d) dp += sH1[t * 32 + d] * pw2[d];
      sc = sigm(dp / npw);
    }
    if (t < 128) { sKey[t] = sc; sIdx[t] = t; }
  }
  bitonic_desc(sKey, sIdx, 128, t);
  if (t < K2_) {
    out[S2_OFF + b * K2_ + t] = sKey[t];
    sVal[t] = sKey[t]; sSel[t] = sIdx[t];
  }
  __syncthreads();
  {  // xk2: reads h2 rows (<100, first half of sH1), writes sXK (no alias)
    int d = t & 31, r0 = t >> 5;
    for (int r = r0; r < K2_; r += 8) sXK[r * 32 + d] = sH1[sSel[r] * 32 + d] * sVal[r];
  }
  __syncthreads();
  if (t < 32) {
    float m = -3.0e38f, s = 0.f;
    for (int r = 0; r < K2_; ++r) { float v = sXK[r * 32 + t]; m = fmaxf(m, v); s += v; }
    sXV[64 + t] = m; sXV[96 + t] = s / 50.f;
  }
  __syncthreads();

  // -------------- Phase G: MLP head --------------
  const float RS = 0.99999500003749969f;   // 1/sqrt(1+1e-5)
  if (t < 32) {
    float z = fc1b[t];
    for (int k = 0; k < 128; ++k) z += sXV[k] * fc1w[k * 32 + t];
    z = fmaxf(z, 0.f);
    z = bn4g[t] * z * RS + bn4b[t];
    sKey[t] = z;
  }
  __syncthreads();
  if (t < 8) {
    float z = fc2b[t];
    for (int k = 0; k < 32; ++k) z += sKey[k] * fc2w[k * 8 + t];
    z = fmaxf(z, 0.f);
    z = bn5g[t] * z * RS + bn5b[t];
    sKey[32 + t] = z;
  }
  __syncthreads();
  if (t < 2) {
    float z = fc3b[t];
    for (int k = 0; k < 8; ++k) z += sKey[32 + k] * fc3w[k * 2 + t];
    sKey[40 + t] = z;
  }
  __syncthreads();
  if (t < 2) {
    float z0 = sKey[40], z1 = sKey[41];
    float m = fmaxf(z0, z1);
    float lse = m + logf(__expf(z0 - m) + __expf(z1 - m));
    out[b * 2 + t] = sKey[40 + t] - lse;
  }
}

extern "C" void kernel_launch(void* const* d_in, const int* in_sizes, int n_in,
                              void* d_out, int out_size, void* d_ws, size_t ws_size,
                              hipStream_t stream) {
  (void)in_sizes; (void)n_in; (void)d_ws; (void)ws_size; (void)out_size;
  const float* x    = (const float*)d_in[0];
  const float* adj  = (const float*)d_in[1];
  const float* W1   = (const float*)d_in[2];
  const float* a1s  = (const float*)d_in[3];
  const float* a1d  = (const float*)d_in[4];
  const float* b1   = (const float*)d_in[5];
  const float* W2   = (const float*)d_in[6];
  const float* a2s  = (const float*)d_in[7];
  const float* a2d  = (const float*)d_in[8];
  const float* b2   = (const float*)d_in[9];
  const float* pw1  = (const float*)d_in[10];
  const float* pw2  = (const float*)d_in[11];
  const float* fc1w = (const float*)d_in[12];
  const float* fc1b = (const float*)d_in[13];
  const float* fc2w = (const float*)d_in[14];
  const float* fc2b = (const float*)d_in[15];
  const float* fc3w = (const float*)d_in[16];
  const float* fc3b = (const float*)d_in[17];
  const float* bn4g = (const float*)d_in[18];
  const float* bn4b = (const float*)d_in[19];
  const float* bn5g = (const float*)d_in[20];
  const float* bn5b = (const float*)d_in[21];

  gnn_fused<<<B_, 256, 0, stream>>>(x, adj, W1, a1s, a1d, b1, W2, a2s, a2d, b2,
                                    pw1, pw2, fc1w, fc1b, fc2w, fc2b, fc3w, fc3b,
                                    bn4g, bn4b, bn5g, bn5b, (float*)d_out);
}